// Round 4
// baseline (255.844 us; speedup 1.0000x reference)
//
#include <hip/hip_runtime.h>
#include <hip/hip_bf16.h>
#include <math.h>

// Shapes (fixed by the reference)
#define B_SZ   256
#define L_SZ   512
#define FD_SZ  64
#define H1_SZ  512
#define H2_SZ  512
#define G_SZ   32
#define DH_SZ  256
#define M_SZ   (B_SZ * L_SZ)   // 131072 rows

#define ROWS   32              // rows per workgroup (32-row tile, 4 blk/CU)

typedef __bf16 bfx8 __attribute__((ext_vector_type(8)));
typedef __bf16 bfx4 __attribute__((ext_vector_type(4)));
typedef float  f32x4 __attribute__((ext_vector_type(4)));

__device__ __forceinline__ float gelu_exact(float x) {
  return 0.5f * x * (1.0f + erff(x * 0.70710678118654752440f));
}
// tanh-form gelu via sigmoid; log2(e) folded in so v_exp_f32 is used directly.
__device__ __forceinline__ float gelu_fast(float x) {
  float x2 = x * x;
  float w = x * fmaf(0.102943398f, x2, 2.30220931f);
  float e = __builtin_amdgcn_exp2f(-w);
  return x * __builtin_amdgcn_rcpf(1.0f + e);
}
__device__ __forceinline__ float softplus_f(float x) {
  return (x > 20.0f) ? x : log1pf(expf(x));
}
__device__ __forceinline__ __bf16 f2bf(float f) { return (__bf16)f; }

// DPP row_ror:n within each 16-lane row (pure VALU, no LDS pipe).
#define ROR_ADD(x, n)                                                          \
  {                                                                            \
    int _t = __builtin_amdgcn_mov_dpp(__builtin_bit_cast(int, (x)),            \
                                      0x120 + (n), 0xF, 0xF, true);            \
    (x) += __builtin_bit_cast(float, _t);                                      \
  }

#define MFMA16(a, b, c) __builtin_amdgcn_mfma_f32_16x16x32_bf16((a), (b), (c), 0, 0, 0)

// ---------------------------------------------------------------------------
// Repack W1 (64x512) and W2 (512x512) fp32 -> bf16 MFMA fragment order.
// Lane l of block holds W[kbase + (l>>4)*8 + j][16*nb + (l&15)], j=0..7.
// W1p block id = mb*2 + ks (mb: H1/16, ks: FD/32). W2p block id = nb*16 + ks.
// ---------------------------------------------------------------------------
__global__ void repack_kernel(const float* __restrict__ W1,
                              const float* __restrict__ W2,
                              __bf16* __restrict__ W1p,
                              __bf16* __restrict__ W2p) {
  int t = blockIdx.x * 256 + threadIdx.x;
  if (t < 4096) {  // W1: 64 blocks * 64 lanes
    int lane = t & 63, blk = t >> 6;
    int ks = blk & 1, mb = blk >> 1;
    int col = 16 * mb + (lane & 15);
    int kbase = ks * 32 + (lane >> 4) * 8;
    bfx8 o;
#pragma unroll
    for (int j = 0; j < 8; ++j) o[j] = f2bf(W1[(size_t)(kbase + j) * H1_SZ + col]);
    *reinterpret_cast<bfx8*>(W1p + (size_t)t * 8) = o;
  } else if (t < 4096 + 32768) {  // W2: 512 blocks * 64 lanes
    int t2 = t - 4096;
    int lane = t2 & 63, blk = t2 >> 6;
    int ks = blk & 15, nb = blk >> 4;
    int col = 16 * nb + (lane & 15);
    int kbase = ks * 32 + (lane >> 4) * 8;
    bfx8 o;
#pragma unroll
    for (int j = 0; j < 8; ++j) o[j] = f2bf(W2[(size_t)(kbase + j) * H2_SZ + col]);
    *reinterpret_cast<bfx8*>(W2p + (size_t)t2 * 8) = o;
  }
}

// ---------------------------------------------------------------------------
// Fused MLP kernel: 32 rows per workgroup, 512 threads (8 waves).
// Wave w owns 64 h-columns (mb/nb = 4w..4w+3), all 32 rows.
//  GEMM1 (transposed: h1^T = W1^T * X^T, X direct from global) -> gelu -> H1s
//  GEMM2 (h1 * W2 from L2) -> gelu -> DPP-reduced absorb/atten + pooled
// LDS 34.5 KB -> 4 blocks/CU -> 32 waves/CU (needs VGPR <= 64).
// ---------------------------------------------------------------------------
__global__ __launch_bounds__(512, 8) void fused_kernel(
    const float* __restrict__ Xl,
    const __bf16* __restrict__ W1p, const __bf16* __restrict__ W2p,
    const float* __restrict__ b1, const float* __restrict__ b2,
    const float* __restrict__ wa, const float* __restrict__ ba,
    const float* __restrict__ wt, const float* __restrict__ bt,
    float* __restrict__ absorbW, float* __restrict__ attenW,
    float* __restrict__ pooled) {
  __shared__ __bf16 H1s[ROWS * 512];   // 32 KB, [row][k] bf16, chunk XOR swizzle
  __shared__ float sl[8 * ROWS * 2];   // 2 KB per-wave {absorb, atten} partials

  const int tid = threadIdx.x;
  const int lane = tid & 63;
  const int w = tid >> 6;        // wave 0..7
  const int g = lane >> 4;       // k-group 0..3
  const int c = lane & 15;       // row/col within fragment
  const int R0 = blockIdx.x * ROWS;
  const int bidx = R0 >> 9;      // batch index (tiles aligned within batch)

  // ---- GEMM1 (transposed): wave computes h1 cols 16*(4w)..16*(4w+3)+15 ----
  f32x4 acc1[4][2];
#pragma unroll
  for (int mi = 0; mi < 4; ++mi)
#pragma unroll
    for (int ni = 0; ni < 2; ++ni) acc1[mi][ni] = (f32x4){0.f, 0.f, 0.f, 0.f};

#pragma unroll
  for (int ks = 0; ks < 2; ++ks) {
    bfx8 a1[4];
#pragma unroll
    for (int mi = 0; mi < 4; ++mi) {
      int mb = 4 * w + mi;
      a1[mi] = *reinterpret_cast<const bfx8*>(W1p + ((size_t)(mb * 2 + ks) * 64 + lane) * 8);
    }
    bfx8 bx[2];
#pragma unroll
    for (int ni = 0; ni < 2; ++ni) {
      // lane needs X[R0 + 16*ni + c][32*ks + 8*g + j], j=0..7 (contiguous fp32)
      const float* xp = Xl + (size_t)(R0 + 16 * ni + c) * FD_SZ + 32 * ks + 8 * g;
      float4 u0 = *reinterpret_cast<const float4*>(xp);
      float4 u1 = *reinterpret_cast<const float4*>(xp + 4);
      bfx8 bv;
      bv[0] = f2bf(u0.x); bv[1] = f2bf(u0.y); bv[2] = f2bf(u0.z); bv[3] = f2bf(u0.w);
      bv[4] = f2bf(u1.x); bv[5] = f2bf(u1.y); bv[6] = f2bf(u1.z); bv[7] = f2bf(u1.w);
      bx[ni] = bv;
    }
#pragma unroll
    for (int mi = 0; mi < 4; ++mi)
#pragma unroll
      for (int ni = 0; ni < 2; ++ni)
        acc1[mi][ni] = MFMA16(a1[mi], bx[ni], acc1[mi][ni]);
  }

  // epilogue GEMM1: bias + gelu -> bf16 -> H1s[row][k] (k = 16*mb + 4*g + reg)
#pragma unroll
  for (int mi = 0; mi < 4; ++mi) {
    int mb = 4 * w + mi;
    float4 bias4 = *reinterpret_cast<const float4*>(b1 + 16 * mb + 4 * g);
#pragma unroll
    for (int ni = 0; ni < 2; ++ni) {
      int r = 16 * ni + c;                 // x-row (0..31)
      bfx4 pv;
      pv[0] = f2bf(gelu_fast(acc1[mi][ni][0] + bias4.x));
      pv[1] = f2bf(gelu_fast(acc1[mi][ni][1] + bias4.y));
      pv[2] = f2bf(gelu_fast(acc1[mi][ni][2] + bias4.z));
      pv[3] = f2bf(gelu_fast(acc1[mi][ni][3] + bias4.w));
      int kchunk = 2 * mb + (g >> 1);      // (16*mb + 4*g)/8
      int off = r * 512 + ((kchunk ^ (r & 7)) << 3) + (g & 1) * 4;
      *reinterpret_cast<bfx4*>(&H1s[off]) = pv;
    }
  }
  __syncthreads();

  // ---- GEMM2: wave computes h2 cols 16*(4w)..16*(4w+3)+15, rows 0..31 ------
  f32x4 acc2[2][4];
#pragma unroll
  for (int m = 0; m < 2; ++m)
#pragma unroll
    for (int ni = 0; ni < 4; ++ni) acc2[m][ni] = (f32x4){0.f, 0.f, 0.f, 0.f};

  for (int ks = 0; ks < 16; ++ks) {
    bfx8 a2[2];
#pragma unroll
    for (int m = 0; m < 2; ++m) {
      int r = 16 * m + c;
      int chunk = 4 * ks + g;
      a2[m] = *reinterpret_cast<const bfx8*>(&H1s[r * 512 + ((chunk ^ (r & 7)) << 3)]);
    }
    bfx8 bw[4];
#pragma unroll
    for (int ni = 0; ni < 4; ++ni) {
      int nb = 4 * w + ni;
      bw[ni] = *reinterpret_cast<const bfx8*>(W2p + ((size_t)(nb * 16 + ks) * 64 + lane) * 8);
    }
#pragma unroll
    for (int ni = 0; ni < 4; ++ni)
#pragma unroll
      for (int m = 0; m < 2; ++m)
        acc2[m][ni] = MFMA16(a2[m], bw[ni], acc2[m][ni]);
  }

  // ---- epilogue GEMM2: bias+gelu, reduce to absorb/atten/pooled ----
  float b2v[4], wav[4], wtv[4];
#pragma unroll
  for (int ni = 0; ni < 4; ++ni) {
    int col = 16 * (4 * w + ni) + c;
    b2v[ni] = b2[col];
    wav[ni] = wa[col];
    wtv[ni] = wt[col];
  }
  float pool[4];
#pragma unroll
  for (int ni = 0; ni < 4; ++ni) pool[ni] = 0.0f;

#pragma unroll
  for (int m = 0; m < 2; ++m) {
#pragma unroll
    for (int reg = 0; reg < 4; ++reg) {
      float sa = 0.0f, st = 0.0f;
#pragma unroll
      for (int ni = 0; ni < 4; ++ni) {
        float v = gelu_fast(acc2[m][ni][reg] + b2v[ni]);
        sa = fmaf(v, wav[ni], sa);
        st = fmaf(v, wtv[ni], st);
        pool[ni] += v;
      }
      // sum over the 16 c-lanes (one DPP row) — VALU only
      ROR_ADD(sa, 8); ROR_ADD(sa, 4); ROR_ADD(sa, 2); ROR_ADD(sa, 1);
      ROR_ADD(st, 8); ROR_ADD(st, 4); ROR_ADD(st, 2); ROR_ADD(st, 1);
      if (c == 0) {
        int row = 16 * m + 4 * g + reg;   // each row exactly once per wave
        float2 v2 = make_float2(sa, st);
        *reinterpret_cast<float2*>(&sl[w * (2 * ROWS) + row * 2]) = v2;
      }
    }
  }
#pragma unroll
  for (int ni = 0; ni < 4; ++ni) {
    float v = pool[ni];
    v += __shfl_xor(v, 16, 64);
    v += __shfl_xor(v, 32, 64);
    if (g == 0) atomicAdd(&pooled[bidx * H2_SZ + 16 * (4 * w + ni) + c], v);
  }
  __syncthreads();

  if (tid < ROWS) {
    float sa = 0.0f, st = 0.0f;
#pragma unroll
    for (int w8 = 0; w8 < 8; ++w8) {
      float2 v2 = *reinterpret_cast<float2*>(&sl[w8 * (2 * ROWS) + tid * 2]);
      sa += v2.x; st += v2.y;
    }
    absorbW[R0 + tid] = softplus_f(sa + ba[0]);
    attenW[R0 + tid]  = softplus_f(st + bt[0]);
  }
}

// ---------------------------------------------------------------------------
// Finalize: per-b reversed exclusive-cumsum scan + captured, pooled head, out
// ---------------------------------------------------------------------------
__global__ __launch_bounds__(256) void finalize_kernel(
    const float* __restrict__ Xg,
    const float* __restrict__ absorbW, const float* __restrict__ attenW,
    const float* __restrict__ pooled,
    const float* __restrict__ Wd1, const float* __restrict__ bd1,
    const float* __restrict__ Wd2, const float* __restrict__ bd2,
    float* __restrict__ out) {
  __shared__ float s0[512];
  __shared__ float s1[512];
  __shared__ float sab[512];
  __shared__ float zz[544];
  __shared__ float redc[4];
  __shared__ float redd[4];

  const int b = blockIdx.x;
  const int t = threadIdx.x;
  const int i0 = t, i1 = t + 256;

  // load time-reversed absorb/atten
  float a0 = attenW[b * L_SZ + (L_SZ - 1 - i0)];
  float a1 = attenW[b * L_SZ + (L_SZ - 1 - i1)];
  sab[i0] = absorbW[b * L_SZ + (L_SZ - 1 - i0)];
  sab[i1] = absorbW[b * L_SZ + (L_SZ - 1 - i1)];
  s0[i0] = a0; s0[i1] = a1;
  __syncthreads();

  // Hillis-Steele inclusive scan (ping-pong)
  float* src = s0;
  float* dst = s1;
  for (int off = 1; off < 512; off <<= 1) {
    float v0 = src[i0] + ((i0 >= off) ? src[i0 - off] : 0.0f);
    float v1 = src[i1] + ((i1 >= off) ? src[i1 - off] : 0.0f);
    dst[i0] = v0; dst[i1] = v1;
    __syncthreads();
    float* tmp = src; src = dst; dst = tmp;
  }

  // captured partials: exp(-(incl - a)) * absorb_tb
  float p = expf(-(src[i0] - a0)) * sab[i0] + expf(-(src[i1] - a1)) * sab[i1];
#pragma unroll
  for (int off = 32; off; off >>= 1) p += __shfl_down(p, off, 64);
  if ((t & 63) == 0) redc[t >> 6] = p;

  // z = [Xg, pooled/L]
  if (t < G_SZ) zz[t] = Xg[b * G_SZ + t];
  zz[G_SZ + i0] = pooled[b * H2_SZ + i0] * (1.0f / (float)L_SZ);
  zz[G_SZ + i1] = pooled[b * H2_SZ + i1] * (1.0f / (float)L_SZ);
  __syncthreads();

  // d1[j] = gelu(z . Wd1[:,j] + bd1[j]);  v = d1[j] * Wd2[j]
  float s = bd1[t];
  for (int cc = 0; cc < G_SZ + H2_SZ; ++cc) s = fmaf(zz[cc], Wd1[cc * DH_SZ + t], s);
  float v = gelu_exact(s) * Wd2[t];
#pragma unroll
  for (int off = 32; off; off >>= 1) v += __shfl_down(v, off, 64);
  if ((t & 63) == 0) redd[t >> 6] = v;
  __syncthreads();

  if (t == 0) {
    float captured = redc[0] + redc[1] + redc[2] + redc[3];
    float d = redd[0] + redd[1] + redd[2] + redd[3] + bd2[0];
    out[b] = captured + d;
  }
}

// ---------------------------------------------------------------------------
extern "C" void kernel_launch(void* const* d_in, const int* in_sizes, int n_in,
                              void* d_out, int out_size, void* d_ws, size_t ws_size,
                              hipStream_t stream) {
  const float* Xg  = (const float*)d_in[0];
  const float* Xl  = (const float*)d_in[1];
  const float* W1  = (const float*)d_in[2];
  const float* b1  = (const float*)d_in[3];
  const float* W2  = (const float*)d_in[4];
  const float* b2  = (const float*)d_in[5];
  const float* wa  = (const float*)d_in[6];
  const float* ba  = (const float*)d_in[7];
  const float* wt  = (const float*)d_in[8];
  const float* bt  = (const float*)d_in[9];
  const float* Wd1 = (const float*)d_in[10];
  const float* bd1 = (const float*)d_in[11];
  const float* Wd2 = (const float*)d_in[12];
  const float* bd2 = (const float*)d_in[13];

  char* ws = (char*)d_ws;
  __bf16* W1p    = (__bf16*)(ws + 0);            //  65536 B
  __bf16* W2p    = (__bf16*)(ws + 65536);        // 524288 B
  float* absorbW = (float*)(ws + 589824);        // 524288 B
  float* attenW  = (float*)(ws + 1114112);       // 524288 B
  float* pooled  = (float*)(ws + 1638400);       // 524288 B  (end 2162688)

  hipMemsetAsync(pooled, 0, B_SZ * H2_SZ * sizeof(float), stream);
  repack_kernel<<<144, 256, 0, stream>>>(W1, W2, W1p, W2p);
  fused_kernel<<<M_SZ / ROWS, 512, 0, stream>>>(Xl, W1p, W2p, b1, b2, wa, ba, wt, bt,
                                                absorbW, attenW, pooled);
  finalize_kernel<<<B_SZ, 256, 0, stream>>>(Xg, absorbW, attenW, pooled,
                                            Wd1, bd1, Wd2, bd2, (float*)d_out);
}

// Round 5
// 240.609 us; speedup vs baseline: 1.0633x; 1.0633x over previous
//
#include <hip/hip_runtime.h>
#include <hip/hip_bf16.h>
#include <math.h>

// Shapes (fixed by the reference)
#define B_SZ   256
#define L_SZ   512
#define FD_SZ  64
#define H1_SZ  512
#define H2_SZ  512
#define G_SZ   32
#define DH_SZ  256

typedef __bf16 bfx8 __attribute__((ext_vector_type(8)));
typedef __bf16 bfx4 __attribute__((ext_vector_type(4)));
typedef float  f32x4 __attribute__((ext_vector_type(4)));

__device__ __forceinline__ float gelu_exact(float x) {
  return 0.5f * x * (1.0f + erff(x * 0.70710678118654752440f));
}
// tanh-form gelu via sigmoid; log2(e) folded in so v_exp_f32 is used directly.
__device__ __forceinline__ float gelu_fast(float x) {
  float x2 = x * x;
  float w = x * fmaf(0.102943398f, x2, 2.30220931f);
  float e = __builtin_amdgcn_exp2f(-w);
  return x * __builtin_amdgcn_rcpf(1.0f + e);
}
__device__ __forceinline__ float softplus_f(float x) {
  return (x > 20.0f) ? x : log1pf(expf(x));
}
__device__ __forceinline__ __bf16 f2bf(float f) { return (__bf16)f; }

// DPP row_ror:n within each 16-lane row (pure VALU, no LDS pipe).
#define ROR_ADD(x, n)                                                          \
  {                                                                            \
    int _t = __builtin_amdgcn_mov_dpp(__builtin_bit_cast(int, (x)),            \
                                      0x120 + (n), 0xF, 0xF, true);            \
    (x) += __builtin_bit_cast(float, _t);                                      \
  }

#define MFMA16(a, b, c) __builtin_amdgcn_mfma_f32_16x16x32_bf16((a), (b), (c), 0, 0, 0)

// ---------------------------------------------------------------------------
// Repack W1 (64x512) and W2 (512x512) fp32 -> bf16 MFMA fragment order.
// Lane l of block holds W[kbase + (l>>4)*8 + j][16*nb + (l&15)], j=0..7.
// W1p block id = mb*2 + ks (mb: H1/16, ks: FD/32). W2p block id = nb*16 + ks.
// ---------------------------------------------------------------------------
__global__ void repack_kernel(const float* __restrict__ W1,
                              const float* __restrict__ W2,
                              __bf16* __restrict__ W1p,
                              __bf16* __restrict__ W2p) {
  int t = blockIdx.x * 256 + threadIdx.x;
  if (t < 4096) {  // W1: 64 blocks * 64 lanes
    int lane = t & 63, blk = t >> 6;
    int ks = blk & 1, mb = blk >> 1;
    int col = 16 * mb + (lane & 15);
    int kbase = ks * 32 + (lane >> 4) * 8;
    bfx8 o;
#pragma unroll
    for (int j = 0; j < 8; ++j) o[j] = f2bf(W1[(size_t)(kbase + j) * H1_SZ + col]);
    *reinterpret_cast<bfx8*>(W1p + (size_t)t * 8) = o;
  } else if (t < 4096 + 32768) {  // W2: 512 blocks * 64 lanes
    int t2 = t - 4096;
    int lane = t2 & 63, blk = t2 >> 6;
    int ks = blk & 15, nb = blk >> 4;
    int col = 16 * nb + (lane & 15);
    int kbase = ks * 32 + (lane >> 4) * 8;
    bfx8 o;
#pragma unroll
    for (int j = 0; j < 8; ++j) o[j] = f2bf(W2[(size_t)(kbase + j) * H2_SZ + col]);
    *reinterpret_cast<bfx8*>(W2p + (size_t)t2 * 8) = o;
  }
}

// ---------------------------------------------------------------------------
// Mega kernel: one block per batch element b. 1024 threads = 16 waves.
// Loop over 4 subtiles of 128 rows:
//   GEMM1 (wave: 32 h1-cols x 128 rows) -> gelu -> H1s (128x512 bf16, LDS)
//   GEMM2 (wave: 32 h2-cols x 128 rows, W2 from L2) -> gelu -> reductions
// Then in-block: softplus, reversed exclusive-cumsum scan, captured, head.
// Register budget: 64 AGPR (acc) + ~60 VGPR = 128/wave -> 4 waves/SIMD.
// ---------------------------------------------------------------------------
__global__ __launch_bounds__(1024, 4) void mega_kernel(
    const float* __restrict__ Xg, const float* __restrict__ Xl,
    const __bf16* __restrict__ W1p, const __bf16* __restrict__ W2p,
    const float* __restrict__ b1, const float* __restrict__ b2,
    const float* __restrict__ wa, const float* __restrict__ ba,
    const float* __restrict__ wt, const float* __restrict__ bt,
    const float* __restrict__ Wd1, const float* __restrict__ bd1,
    const float* __restrict__ Wd2, const float* __restrict__ bd2,
    float* __restrict__ out) {
  __shared__ __bf16 H1s[128 * 512];   // 128 KB; reused as scan floats later
  __shared__ float absorb_l[512];
  __shared__ float atten_l[512];
  __shared__ float pooled_l[512];
  __shared__ float zz[544];
  __shared__ float redc[16];
  __shared__ float redd[16];

  const int tid = threadIdx.x;
  const int lane = tid & 63;
  const int w = tid >> 6;        // wave 0..15
  const int g = lane >> 4;       // k-group 0..3
  const int c = lane & 15;       // row/col within fragment
  const int b = blockIdx.x;

  if (tid < 512) { absorb_l[tid] = 0.0f; atten_l[tid] = 0.0f; }

  // constant per-column epilogue weights (cols 16*(2w+ni)+c)
  float b2v[2], wav[2], wtv[2];
#pragma unroll
  for (int ni = 0; ni < 2; ++ni) {
    int col = 16 * (2 * w + ni) + c;
    b2v[ni] = b2[col];
    wav[ni] = wa[col];
    wtv[ni] = wt[col];
  }
  float pool0 = 0.0f, pool1 = 0.0f;

  for (int st = 0; st < 4; ++st) {
    const int R0 = b * L_SZ + st * 128;
    __syncthreads();   // H1s free of previous subtile's readers (+init fence)

    // ---- GEMM1: wave computes h1 cols 16*(2w)..16*(2w+1)+15, 128 rows ----
    f32x4 acc1[2][8];
#pragma unroll
    for (int mi = 0; mi < 2; ++mi)
#pragma unroll
      for (int ni = 0; ni < 8; ++ni) acc1[mi][ni] = (f32x4){0.f, 0.f, 0.f, 0.f};

#pragma unroll
    for (int ks = 0; ks < 2; ++ks) {
      bfx8 a1[2];
#pragma unroll
      for (int mi = 0; mi < 2; ++mi) {
        int mb = 2 * w + mi;
        a1[mi] = *reinterpret_cast<const bfx8*>(W1p + ((size_t)(mb * 2 + ks) * 64 + lane) * 8);
      }
#pragma unroll
      for (int ni = 0; ni < 8; ++ni) {
        const float* xp = Xl + (size_t)(R0 + 16 * ni + c) * FD_SZ + 32 * ks + 8 * g;
        float4 u0 = *reinterpret_cast<const float4*>(xp);
        float4 u1 = *reinterpret_cast<const float4*>(xp + 4);
        bfx8 bv;
        bv[0] = f2bf(u0.x); bv[1] = f2bf(u0.y); bv[2] = f2bf(u0.z); bv[3] = f2bf(u0.w);
        bv[4] = f2bf(u1.x); bv[5] = f2bf(u1.y); bv[6] = f2bf(u1.z); bv[7] = f2bf(u1.w);
        acc1[0][ni] = MFMA16(a1[0], bv, acc1[0][ni]);
        acc1[1][ni] = MFMA16(a1[1], bv, acc1[1][ni]);
      }
    }

    // epilogue1: bias + gelu -> bf16 -> H1s[row][k], k = 16*mb + 4*g + reg
#pragma unroll
    for (int mi = 0; mi < 2; ++mi) {
      int mb = 2 * w + mi;
      float4 bias4 = *reinterpret_cast<const float4*>(b1 + 16 * mb + 4 * g);
#pragma unroll
      for (int ni = 0; ni < 8; ++ni) {
        int r = 16 * ni + c;               // 0..127
        bfx4 pv;
        pv[0] = f2bf(gelu_fast(acc1[mi][ni][0] + bias4.x));
        pv[1] = f2bf(gelu_fast(acc1[mi][ni][1] + bias4.y));
        pv[2] = f2bf(gelu_fast(acc1[mi][ni][2] + bias4.z));
        pv[3] = f2bf(gelu_fast(acc1[mi][ni][3] + bias4.w));
        int kchunk = 2 * mb + (g >> 1);
        int off = r * 512 + ((kchunk ^ (r & 7)) << 3) + (g & 1) * 4;
        *reinterpret_cast<bfx4*>(&H1s[off]) = pv;
      }
    }
    __syncthreads();

    // ---- GEMM2: wave computes h2 cols 16*(2w)..16*(2w+1)+15, 128 rows ----
    f32x4 acc2[8][2];
#pragma unroll
    for (int m = 0; m < 8; ++m)
#pragma unroll
      for (int ni = 0; ni < 2; ++ni) acc2[m][ni] = (f32x4){0.f, 0.f, 0.f, 0.f};

    const __bf16* wpb = W2p + ((size_t)(2 * w) * 16 * 64 + lane) * 8;
    for (int ks = 0; ks < 16; ++ks) {
      bfx8 bw0 = *reinterpret_cast<const bfx8*>(wpb + ks * 512);
      bfx8 bw1 = *reinterpret_cast<const bfx8*>(wpb + 8192 + ks * 512);
#pragma unroll
      for (int m = 0; m < 8; ++m) {
        int r = 16 * m + c;
        int chunk = 4 * ks + g;
        bfx8 a2 = *reinterpret_cast<const bfx8*>(&H1s[r * 512 + ((chunk ^ (r & 7)) << 3)]);
        acc2[m][0] = MFMA16(a2, bw0, acc2[m][0]);
        acc2[m][1] = MFMA16(a2, bw1, acc2[m][1]);
      }
    }

    // epilogue2: bias+gelu, reduce to absorb/atten (LDS atomics) + pooled
#pragma unroll
    for (int m = 0; m < 8; ++m) {
#pragma unroll
      for (int reg = 0; reg < 4; ++reg) {
        float v0 = gelu_fast(acc2[m][0][reg] + b2v[0]);
        float v1 = gelu_fast(acc2[m][1][reg] + b2v[1]);
        float sa = v0 * wav[0] + v1 * wav[1];
        float stv = v0 * wtv[0] + v1 * wtv[1];
        pool0 += v0;
        pool1 += v1;
        ROR_ADD(sa, 8); ROR_ADD(sa, 4); ROR_ADD(sa, 2); ROR_ADD(sa, 1);
        ROR_ADD(stv, 8); ROR_ADD(stv, 4); ROR_ADD(stv, 2); ROR_ADD(stv, 1);
        if (c == 0) {
          int row = st * 128 + 16 * m + 4 * g + reg;
          atomicAdd(&absorb_l[row], sa);
          atomicAdd(&atten_l[row], stv);
        }
      }
    }
  }

  // ---- pooled: reduce across g-groups, write LDS ----
  pool0 += __shfl_xor(pool0, 16, 64); pool0 += __shfl_xor(pool0, 32, 64);
  pool1 += __shfl_xor(pool1, 16, 64); pool1 += __shfl_xor(pool1, 32, 64);
  if (g == 0) {
    pooled_l[16 * (2 * w) + c]     = pool0;
    pooled_l[16 * (2 * w + 1) + c] = pool1;
  }
  __syncthreads();   // absorb_l/atten_l/pooled_l complete; H1s dead

  // ---- softplus + reversed scan setup (reuse H1s region as floats) ----
  float* sc = reinterpret_cast<float*>(H1s);
  float* s0 = sc;
  float* s1 = sc + 512;
  float av = 0.0f, sabv = 0.0f;
  if (tid < 512) {
    av   = softplus_f(atten_l[511 - tid] + bt[0]);
    sabv = softplus_f(absorb_l[511 - tid] + ba[0]);
    s0[tid] = av;
    zz[G_SZ + tid] = pooled_l[tid] * (1.0f / (float)L_SZ);
  }
  if (tid < G_SZ) zz[tid] = Xg[b * G_SZ + tid];
  __syncthreads();

  // Hillis-Steele inclusive scan over 512 (threads 0..511), ping-pong
  float* src = s0;
  float* dst = s1;
  for (int off = 1; off < 512; off <<= 1) {
    if (tid < 512) dst[tid] = src[tid] + ((tid >= off) ? src[tid - off] : 0.0f);
    __syncthreads();
    float* tmp = src; src = dst; dst = tmp;
  }

  // captured partials: exp(-(incl - a)) * absorb_tb
  float p = 0.0f;
  if (tid < 512) p = __expf(-(src[tid] - av)) * sabv;
#pragma unroll
  for (int off = 32; off; off >>= 1) p += __shfl_down(p, off, 64);
  if (lane == 0) redc[w] = p;
  __syncthreads();

  // head: d1[j] = gelu(z . Wd1[:,j] + bd1[j]); dv = d1[j] * Wd2[j]
  float dv = 0.0f;
  if (tid < DH_SZ) {
    float s = bd1[tid];
    for (int cc = 0; cc < G_SZ + H2_SZ; ++cc)
      s = fmaf(zz[cc], Wd1[(size_t)cc * DH_SZ + tid], s);
    dv = gelu_exact(s) * Wd2[tid];
  }
#pragma unroll
  for (int off = 32; off; off >>= 1) dv += __shfl_down(dv, off, 64);
  if (lane == 0) redd[w] = dv;
  __syncthreads();

  if (tid == 0) {
    float captured = 0.0f, d = bd2[0];
#pragma unroll
    for (int i = 0; i < 16; ++i) { captured += redc[i]; d += redd[i]; }
    out[b] = captured + d;
  }
}

// ---------------------------------------------------------------------------
extern "C" void kernel_launch(void* const* d_in, const int* in_sizes, int n_in,
                              void* d_out, int out_size, void* d_ws, size_t ws_size,
                              hipStream_t stream) {
  const float* Xg  = (const float*)d_in[0];
  const float* Xl  = (const float*)d_in[1];
  const float* W1  = (const float*)d_in[2];
  const float* b1  = (const float*)d_in[3];
  const float* W2  = (const float*)d_in[4];
  const float* b2  = (const float*)d_in[5];
  const float* wa  = (const float*)d_in[6];
  const float* ba  = (const float*)d_in[7];
  const float* wt  = (const float*)d_in[8];
  const float* bt  = (const float*)d_in[9];
  const float* Wd1 = (const float*)d_in[10];
  const float* bd1 = (const float*)d_in[11];
  const float* Wd2 = (const float*)d_in[12];
  const float* bd2 = (const float*)d_in[13];

  char* ws = (char*)d_ws;
  __bf16* W1p = (__bf16*)(ws + 0);        //  65536 B
  __bf16* W2p = (__bf16*)(ws + 65536);    // 524288 B

  repack_kernel<<<144, 256, 0, stream>>>(W1, W2, W1p, W2p);
  mega_kernel<<<B_SZ, 1024, 0, stream>>>(Xg, Xl, W1p, W2p, b1, b2, wa, ba, wt, bt,
                                         Wd1, bd1, Wd2, bd2, (float*)d_out);
}

// Round 6
// 157.077 us; speedup vs baseline: 1.6288x; 1.5318x over previous
//
#include <hip/hip_runtime.h>
#include <hip/hip_bf16.h>
#include <math.h>

// Shapes (fixed by the reference)
#define B_SZ   256
#define L_SZ   512
#define FD_SZ  64
#define H1_SZ  512
#define H2_SZ  512
#define G_SZ   32
#define DH_SZ  256
#define M_SZ   (B_SZ * L_SZ)   // 131072 rows

typedef __bf16 bfx8 __attribute__((ext_vector_type(8)));
typedef __bf16 bfx4 __attribute__((ext_vector_type(4)));
typedef float  f32x4 __attribute__((ext_vector_type(4)));

__device__ __forceinline__ float gelu_exact(float x) {
  return 0.5f * x * (1.0f + erff(x * 0.70710678118654752440f));
}
// tanh-form gelu via sigmoid; log2(e) folded in so v_exp_f32 is used directly.
__device__ __forceinline__ float gelu_fast(float x) {
  float x2 = x * x;
  float w = x * fmaf(0.102943398f, x2, 2.30220931f);
  float e = __builtin_amdgcn_exp2f(-w);
  return x * __builtin_amdgcn_rcpf(1.0f + e);
}
__device__ __forceinline__ float softplus_f(float x) {
  return (x > 20.0f) ? x : log1pf(expf(x));
}
__device__ __forceinline__ __bf16 f2bf(float f) { return (__bf16)f; }

// DPP row_ror:n within each 16-lane row (pure VALU, no LDS pipe).
#define ROR_ADD(x, n)                                                          \
  {                                                                            \
    int _t = __builtin_amdgcn_mov_dpp(__builtin_bit_cast(int, (x)),            \
                                      0x120 + (n), 0xF, 0xF, true);            \
    (x) += __builtin_bit_cast(float, _t);                                      \
  }

#define MFMA16(a, b, c) __builtin_amdgcn_mfma_f32_16x16x32_bf16((a), (b), (c), 0, 0, 0)

// ---------------------------------------------------------------------------
// Repack W1 (64x512) and W2 (512x512) fp32 -> bf16 MFMA fragment order.
// Lane l of block holds W[kbase + (l>>4)*8 + j][16*nb + (l&15)], j=0..7.
// W1p block id = mb*2 + ks (mb: H1/16, ks: FD/32). W2p block id = nb*16 + ks.
// Also zeroes the `pooled` accumulator (512 KB) so no separate memset.
// ---------------------------------------------------------------------------
__global__ void repack_kernel(const float* __restrict__ W1,
                              const float* __restrict__ W2,
                              __bf16* __restrict__ W1p,
                              __bf16* __restrict__ W2p,
                              float* __restrict__ pooled) {
  int t = blockIdx.x * 256 + threadIdx.x;
  // zero pooled: 131072 floats = 32768 float4
  if (t < 32768)
    *reinterpret_cast<float4*>(pooled + (size_t)t * 4) = (float4){0.f, 0.f, 0.f, 0.f};
  if (t < 4096) {  // W1: 64 blocks * 64 lanes
    int lane = t & 63, blk = t >> 6;
    int ks = blk & 1, mb = blk >> 1;
    int col = 16 * mb + (lane & 15);
    int kbase = ks * 32 + (lane >> 4) * 8;
    bfx8 o;
#pragma unroll
    for (int j = 0; j < 8; ++j) o[j] = f2bf(W1[(size_t)(kbase + j) * H1_SZ + col]);
    *reinterpret_cast<bfx8*>(W1p + (size_t)t * 8) = o;
  } else if (t < 4096 + 32768) {  // W2: 512 blocks * 64 lanes
    int t2 = t - 4096;
    int lane = t2 & 63, blk = t2 >> 6;
    int ks = blk & 15, nb = blk >> 4;
    int col = 16 * nb + (lane & 15);
    int kbase = ks * 32 + (lane >> 4) * 8;
    bfx8 o;
#pragma unroll
    for (int j = 0; j < 8; ++j) o[j] = f2bf(W2[(size_t)(kbase + j) * H2_SZ + col]);
    *reinterpret_cast<bfx8*>(W2p + (size_t)t2 * 8) = o;
  }
}

// ---------------------------------------------------------------------------
// Fused MLP kernel: 64 rows per workgroup, 512 threads (8 waves).
// Wave w owns 64 h-columns (mb/nb = 4w..4w+3).
//  GEMM1 (transposed: h1^T = W1^T * X^T, X direct from global) -> gelu -> H1s
//  GEMM2 (h1 * W2, W2 frags prefetched 1 ks ahead, rolled loop) -> gelu ->
//  DPP-reduced absorb/atten + pooled.
// launch_bounds(512,3): reg budget ~170 so the +16V prefetch CANNOT spill;
// worst case 3 waves/SIMD.
// ---------------------------------------------------------------------------
__global__ __launch_bounds__(512, 3) void fused_kernel(
    const float* __restrict__ Xl,
    const __bf16* __restrict__ W1p, const __bf16* __restrict__ W2p,
    const float* __restrict__ b1, const float* __restrict__ b2,
    const float* __restrict__ wa, const float* __restrict__ ba,
    const float* __restrict__ wt, const float* __restrict__ bt,
    float* __restrict__ absorbW, float* __restrict__ attenW,
    float* __restrict__ pooled) {
  __shared__ __bf16 H1s[64 * 512];    // 64 KB, [row][k] bf16, chunk XOR swizzle
  __shared__ float sl[8 * 64 * 2];    // 4 KB per-wave {absorb, atten} partials

  const int tid = threadIdx.x;
  const int lane = tid & 63;
  const int w = tid >> 6;        // wave 0..7
  const int g = lane >> 4;       // k-group 0..3
  const int c = lane & 15;       // row/col within fragment
  const int R0 = blockIdx.x * 64;
  const int bidx = R0 >> 9;      // batch index (tiles aligned within batch)

  // ---- GEMM1 (transposed): wave computes h1 cols 16*(4w)..16*(4w+3)+15 ----
  f32x4 acc1[4][4];
#pragma unroll
  for (int mi = 0; mi < 4; ++mi)
#pragma unroll
    for (int ni = 0; ni < 4; ++ni) acc1[mi][ni] = (f32x4){0.f, 0.f, 0.f, 0.f};

#pragma unroll
  for (int ks = 0; ks < 2; ++ks) {
    bfx8 a1[4];
#pragma unroll
    for (int mi = 0; mi < 4; ++mi) {
      int mb = 4 * w + mi;
      a1[mi] = *reinterpret_cast<const bfx8*>(W1p + ((size_t)(mb * 2 + ks) * 64 + lane) * 8);
    }
    bfx8 bx[4];
#pragma unroll
    for (int ni = 0; ni < 4; ++ni) {
      // lane needs X[R0 + 16*ni + c][32*ks + 8*g + j], j=0..7 (contiguous fp32)
      const float* xp = Xl + (size_t)(R0 + 16 * ni + c) * FD_SZ + 32 * ks + 8 * g;
      float4 u0 = *reinterpret_cast<const float4*>(xp);
      float4 u1 = *reinterpret_cast<const float4*>(xp + 4);
      bfx8 bv;
      bv[0] = f2bf(u0.x); bv[1] = f2bf(u0.y); bv[2] = f2bf(u0.z); bv[3] = f2bf(u0.w);
      bv[4] = f2bf(u1.x); bv[5] = f2bf(u1.y); bv[6] = f2bf(u1.z); bv[7] = f2bf(u1.w);
      bx[ni] = bv;
    }
#pragma unroll
    for (int mi = 0; mi < 4; ++mi)
#pragma unroll
      for (int ni = 0; ni < 4; ++ni)
        acc1[mi][ni] = MFMA16(a1[mi], bx[ni], acc1[mi][ni]);
  }

  // epilogue GEMM1: bias + gelu -> bf16 -> H1s[row][k] (k = 16*mb + 4*g + reg)
#pragma unroll
  for (int mi = 0; mi < 4; ++mi) {
    int mb = 4 * w + mi;
    float4 bias4 = *reinterpret_cast<const float4*>(b1 + 16 * mb + 4 * g);
#pragma unroll
    for (int ni = 0; ni < 4; ++ni) {
      int r = 16 * ni + c;                 // x-row (0..63)
      bfx4 pv;
      pv[0] = f2bf(gelu_fast(acc1[mi][ni][0] + bias4.x));
      pv[1] = f2bf(gelu_fast(acc1[mi][ni][1] + bias4.y));
      pv[2] = f2bf(gelu_fast(acc1[mi][ni][2] + bias4.z));
      pv[3] = f2bf(gelu_fast(acc1[mi][ni][3] + bias4.w));
      int kchunk = 2 * mb + (g >> 1);      // (16*mb + 4*g)/8
      int off = r * 512 + ((kchunk ^ (r & 7)) << 3) + (g & 1) * 4;
      *reinterpret_cast<bfx4*>(&H1s[off]) = pv;
    }
  }
  __syncthreads();

  // ---- GEMM2: wave computes h2 cols 16*(4w)..16*(4w+3)+15, rows 0..63 ------
  // W2 fragments prefetched one ks-step ahead; ROLLED loop (no unroll) so the
  // in-flight set stays at one extra frag buffer (+16 VGPR, no spill).
  f32x4 acc2[4][4];
#pragma unroll
  for (int m = 0; m < 4; ++m)
#pragma unroll
    for (int ni = 0; ni < 4; ++ni) acc2[m][ni] = (f32x4){0.f, 0.f, 0.f, 0.f};

  const __bf16* wpb = W2p + ((size_t)(4 * w) * 16 * 64 + lane) * 8;
  bfx8 bw[4];
#pragma unroll
  for (int ni = 0; ni < 4; ++ni)
    bw[ni] = *reinterpret_cast<const bfx8*>(wpb + (size_t)ni * 8192);

#pragma unroll 1
  for (int ks = 0; ks < 15; ++ks) {
    bfx8 a2[4];
#pragma unroll
    for (int m = 0; m < 4; ++m) {
      int r = 16 * m + c;
      int chunk = 4 * ks + g;
      a2[m] = *reinterpret_cast<const bfx8*>(&H1s[r * 512 + ((chunk ^ (r & 7)) << 3)]);
    }
    bfx8 bwn[4];
#pragma unroll
    for (int ni = 0; ni < 4; ++ni)
      bwn[ni] = *reinterpret_cast<const bfx8*>(wpb + (size_t)ni * 8192 + (ks + 1) * 512);
#pragma unroll
    for (int ni = 0; ni < 4; ++ni)
#pragma unroll
      for (int m = 0; m < 4; ++m)
        acc2[m][ni] = MFMA16(a2[m], bw[ni], acc2[m][ni]);
#pragma unroll
    for (int ni = 0; ni < 4; ++ni) bw[ni] = bwn[ni];
  }
  {  // peeled last iteration (ks = 15), no prefetch
    bfx8 a2[4];
#pragma unroll
    for (int m = 0; m < 4; ++m) {
      int r = 16 * m + c;
      int chunk = 4 * 15 + g;
      a2[m] = *reinterpret_cast<const bfx8*>(&H1s[r * 512 + ((chunk ^ (r & 7)) << 3)]);
    }
#pragma unroll
    for (int ni = 0; ni < 4; ++ni)
#pragma unroll
      for (int m = 0; m < 4; ++m)
        acc2[m][ni] = MFMA16(a2[m], bw[ni], acc2[m][ni]);
  }

  // ---- epilogue GEMM2: bias+gelu, reduce to absorb/atten/pooled ----
  float b2v[4], wav[4], wtv[4];
#pragma unroll
  for (int ni = 0; ni < 4; ++ni) {
    int col = 16 * (4 * w + ni) + c;
    b2v[ni] = b2[col];
    wav[ni] = wa[col];
    wtv[ni] = wt[col];
  }
  float pool[4];
#pragma unroll
  for (int ni = 0; ni < 4; ++ni) pool[ni] = 0.0f;

#pragma unroll
  for (int m = 0; m < 4; ++m) {
#pragma unroll
    for (int reg = 0; reg < 4; ++reg) {
      float sa = 0.0f, st = 0.0f;
#pragma unroll
      for (int ni = 0; ni < 4; ++ni) {
        float v = gelu_fast(acc2[m][ni][reg] + b2v[ni]);
        sa = fmaf(v, wav[ni], sa);
        st = fmaf(v, wtv[ni], st);
        pool[ni] += v;
      }
      // sum over the 16 c-lanes (one DPP row) — VALU only
      ROR_ADD(sa, 8); ROR_ADD(sa, 4); ROR_ADD(sa, 2); ROR_ADD(sa, 1);
      ROR_ADD(st, 8); ROR_ADD(st, 4); ROR_ADD(st, 2); ROR_ADD(st, 1);
      if (c == 0) {
        int row = 16 * m + 4 * g + reg;   // each row exactly once per wave
        float2 v2 = make_float2(sa, st);
        *reinterpret_cast<float2*>(&sl[w * 128 + row * 2]) = v2;
      }
    }
  }
#pragma unroll
  for (int ni = 0; ni < 4; ++ni) {
    float v = pool[ni];
    v += __shfl_xor(v, 16, 64);
    v += __shfl_xor(v, 32, 64);
    if (g == 0) atomicAdd(&pooled[bidx * H2_SZ + 16 * (4 * w + ni) + c], v);
  }
  __syncthreads();

  if (tid < 64) {
    float sa = 0.0f, st = 0.0f;
#pragma unroll
    for (int w8 = 0; w8 < 8; ++w8) {
      float2 v2 = *reinterpret_cast<float2*>(&sl[w8 * 128 + tid * 2]);
      sa += v2.x; st += v2.y;
    }
    absorbW[R0 + tid] = softplus_f(sa + ba[0]);
    attenW[R0 + tid]  = softplus_f(st + bt[0]);
  }
}

// ---------------------------------------------------------------------------
// Finalize: per-b reversed exclusive-cumsum scan + captured, pooled head, out
// ---------------------------------------------------------------------------
__global__ __launch_bounds__(256) void finalize_kernel(
    const float* __restrict__ Xg,
    const float* __restrict__ absorbW, const float* __restrict__ attenW,
    const float* __restrict__ pooled,
    const float* __restrict__ Wd1, const float* __restrict__ bd1,
    const float* __restrict__ Wd2, const float* __restrict__ bd2,
    float* __restrict__ out) {
  __shared__ float s0[512];
  __shared__ float s1[512];
  __shared__ float sab[512];
  __shared__ float zz[544];
  __shared__ float redc[4];
  __shared__ float redd[4];

  const int b = blockIdx.x;
  const int t = threadIdx.x;
  const int i0 = t, i1 = t + 256;

  // load time-reversed absorb/atten
  float a0 = attenW[b * L_SZ + (L_SZ - 1 - i0)];
  float a1 = attenW[b * L_SZ + (L_SZ - 1 - i1)];
  sab[i0] = absorbW[b * L_SZ + (L_SZ - 1 - i0)];
  sab[i1] = absorbW[b * L_SZ + (L_SZ - 1 - i1)];
  s0[i0] = a0; s0[i1] = a1;
  __syncthreads();

  // Hillis-Steele inclusive scan (ping-pong)
  float* src = s0;
  float* dst = s1;
  for (int off = 1; off < 512; off <<= 1) {
    float v0 = src[i0] + ((i0 >= off) ? src[i0 - off] : 0.0f);
    float v1 = src[i1] + ((i1 >= off) ? src[i1 - off] : 0.0f);
    dst[i0] = v0; dst[i1] = v1;
    __syncthreads();
    float* tmp = src; src = dst; dst = tmp;
  }

  // captured partials: exp(-(incl - a)) * absorb_tb
  float p = expf(-(src[i0] - a0)) * sab[i0] + expf(-(src[i1] - a1)) * sab[i1];
#pragma unroll
  for (int off = 32; off; off >>= 1) p += __shfl_down(p, off, 64);
  if ((t & 63) == 0) redc[t >> 6] = p;

  // z = [Xg, pooled/L]
  if (t < G_SZ) zz[t] = Xg[b * G_SZ + t];
  zz[G_SZ + i0] = pooled[b * H2_SZ + i0] * (1.0f / (float)L_SZ);
  zz[G_SZ + i1] = pooled[b * H2_SZ + i1] * (1.0f / (float)L_SZ);
  __syncthreads();

  // d1[j] = gelu(z . Wd1[:,j] + bd1[j]);  v = d1[j] * Wd2[j]
  float s = bd1[t];
  for (int cc = 0; cc < G_SZ + H2_SZ; ++cc) s = fmaf(zz[cc], Wd1[cc * DH_SZ + t], s);
  float v = gelu_exact(s) * Wd2[t];
#pragma unroll
  for (int off = 32; off; off >>= 1) v += __shfl_down(v, off, 64);
  if ((t & 63) == 0) redd[t >> 6] = v;
  __syncthreads();

  if (t == 0) {
    float captured = redc[0] + redc[1] + redc[2] + redc[3];
    float d = redd[0] + redd[1] + redd[2] + redd[3] + bd2[0];
    out[b] = captured + d;
  }
}

// ---------------------------------------------------------------------------
extern "C" void kernel_launch(void* const* d_in, const int* in_sizes, int n_in,
                              void* d_out, int out_size, void* d_ws, size_t ws_size,
                              hipStream_t stream) {
  const float* Xg  = (const float*)d_in[0];
  const float* Xl  = (const float*)d_in[1];
  const float* W1  = (const float*)d_in[2];
  const float* b1  = (const float*)d_in[3];
  const float* W2  = (const float*)d_in[4];
  const float* b2  = (const float*)d_in[5];
  const float* wa  = (const float*)d_in[6];
  const float* ba  = (const float*)d_in[7];
  const float* wt  = (const float*)d_in[8];
  const float* bt  = (const float*)d_in[9];
  const float* Wd1 = (const float*)d_in[10];
  const float* bd1 = (const float*)d_in[11];
  const float* Wd2 = (const float*)d_in[12];
  const float* bd2 = (const float*)d_in[13];

  char* ws = (char*)d_ws;
  __bf16* W1p    = (__bf16*)(ws + 0);            //  65536 B
  __bf16* W2p    = (__bf16*)(ws + 65536);        // 524288 B
  float* absorbW = (float*)(ws + 589824);        // 524288 B
  float* attenW  = (float*)(ws + 1114112);       // 524288 B
  float* pooled  = (float*)(ws + 1638400);       // 524288 B  (end 2162688)

  repack_kernel<<<144, 256, 0, stream>>>(W1, W2, W1p, W2p, pooled);
  fused_kernel<<<M_SZ / 64, 512, 0, stream>>>(Xl, W1p, W2p, b1, b2, wa, ba, wt, bt,
                                              absorbW, attenW, pooled);
  finalize_kernel<<<B_SZ, 256, 0, stream>>>(Xg, absorbW, attenW, pooled,
                                            Wd1, bd1, Wd2, bd2, (float*)d_out);
}

// Round 7
// 140.090 us; speedup vs baseline: 1.8263x; 1.1213x over previous
//
#include <hip/hip_runtime.h>
#include <hip/hip_bf16.h>
#include <math.h>

// Shapes (fixed by the reference)
#define B_SZ   256
#define L_SZ   512
#define FD_SZ  64
#define H1_SZ  512
#define H2_SZ  512
#define G_SZ   32
#define DH_SZ  256
#define M_SZ   (B_SZ * L_SZ)   // 131072 rows

typedef __bf16 bfx8 __attribute__((ext_vector_type(8)));
typedef __bf16 bfx4 __attribute__((ext_vector_type(4)));
typedef float  f32x4 __attribute__((ext_vector_type(4)));
typedef float  f32x16 __attribute__((ext_vector_type(16)));

__device__ __forceinline__ float gelu_exact(float x) {
  return 0.5f * x * (1.0f + erff(x * 0.70710678118654752440f));
}
// tanh-form gelu via sigmoid; log2(e) folded in so v_exp_f32 is used directly.
__device__ __forceinline__ float gelu_fast(float x) {
  float x2 = x * x;
  float w = x * fmaf(0.102943398f, x2, 2.30220931f);
  float e = __builtin_amdgcn_exp2f(-w);
  return x * __builtin_amdgcn_rcpf(1.0f + e);
}
__device__ __forceinline__ float softplus_f(float x) {
  return (x > 20.0f) ? x : log1pf(expf(x));
}
__device__ __forceinline__ __bf16 f2bf(float f) { return (__bf16)f; }

// DPP row_ror:n within each 16-lane row (pure VALU, no LDS pipe).
#define ROR_ADD(x, n)                                                          \
  {                                                                            \
    int _t = __builtin_amdgcn_mov_dpp(__builtin_bit_cast(int, (x)),            \
                                      0x120 + (n), 0xF, 0xF, true);            \
    (x) += __builtin_bit_cast(float, _t);                                      \
  }

#define MFMA16(a, b, c) __builtin_amdgcn_mfma_f32_16x16x32_bf16((a), (b), (c), 0, 0, 0)
#define MFMA32(a, b, c) __builtin_amdgcn_mfma_f32_32x32x16_bf16((a), (b), (c), 0, 0, 0)

// ---------------------------------------------------------------------------
// Repack W1 (64x512) fp32 -> bf16 16x16x32-B-fragment order:
//   block id = mb*2 + ks (mb: H1/16, ks: FD/32); lane l holds
//   W1[ks*32 + (l>>4)*8 + j][16*mb + (l&15)], j=0..7.
// Repack W2 (512x512) fp32 -> bf16 32x32x16-B-fragment order:
//   block id = nb*32 + ks (nb: H2/32, ks: H1/16); lane l holds
//   W2[16*ks + (l>>5)*8 + j][32*nb + (l&31)], j=0..7.
// Also zeroes the `pooled` accumulator (512 KB) so no separate memset.
// ---------------------------------------------------------------------------
__global__ void repack_kernel(const float* __restrict__ W1,
                              const float* __restrict__ W2,
                              __bf16* __restrict__ W1p,
                              __bf16* __restrict__ W2p,
                              float* __restrict__ pooled) {
  int t = blockIdx.x * 256 + threadIdx.x;
  // zero pooled: 131072 floats = 32768 float4
  if (t < 32768)
    *reinterpret_cast<float4*>(pooled + (size_t)t * 4) = (float4){0.f, 0.f, 0.f, 0.f};
  if (t < 4096) {  // W1: 64 blocks * 64 lanes
    int lane = t & 63, blk = t >> 6;
    int ks = blk & 1, mb = blk >> 1;
    int col = 16 * mb + (lane & 15);
    int kbase = ks * 32 + (lane >> 4) * 8;
    bfx8 o;
#pragma unroll
    for (int j = 0; j < 8; ++j) o[j] = f2bf(W1[(size_t)(kbase + j) * H1_SZ + col]);
    *reinterpret_cast<bfx8*>(W1p + (size_t)t * 8) = o;
  } else if (t < 4096 + 32768) {  // W2: 512 blocks * 64 lanes (32x32x16 frags)
    int t2 = t - 4096;
    int lane = t2 & 63, blk = t2 >> 6;
    int ks = blk & 31, nb = blk >> 5;
    int col = 32 * nb + (lane & 31);
    int kbase = 16 * ks + (lane >> 5) * 8;
    bfx8 o;
#pragma unroll
    for (int j = 0; j < 8; ++j) o[j] = f2bf(W2[(size_t)(kbase + j) * H2_SZ + col]);
    *reinterpret_cast<bfx8*>(W2p + (size_t)t2 * 8) = o;
  }
}

// ---------------------------------------------------------------------------
// Fused MLP kernel: 64 rows per workgroup, 512 threads (8 waves).
//  Stage X tile (64x64) -> bf16 LDS (one convert, shared by all waves).
//  GEMM1 (transposed, 16x16x32): h1^T = W1^T * X^T -> gelu -> H1s.
//  GEMM2 (32x32x16): wave w owns 64 h2-cols (nb = 2w, 2w+1), rows 0..63,
//    K=512; W2 frags from L2 -> gelu -> DPP-reduced absorb/atten + pooled.
// Register budget: 64 AGPR acc + ~60 VGPR = 128 -> 4 waves/SIMD (proven pt).
// ---------------------------------------------------------------------------
__global__ __launch_bounds__(512, 4) void fused_kernel(
    const float* __restrict__ Xl,
    const __bf16* __restrict__ W1p, const __bf16* __restrict__ W2p,
    const float* __restrict__ b1, const float* __restrict__ b2,
    const float* __restrict__ wa, const float* __restrict__ ba,
    const float* __restrict__ wt, const float* __restrict__ bt,
    float* __restrict__ absorbW, float* __restrict__ attenW,
    float* __restrict__ pooled) {
  __shared__ __bf16 Xs[64 * 64];      // 8 KB, [row][k], 16B-chunk XOR swizzle
  __shared__ __bf16 H1s[64 * 512];    // 64 KB, [row][k], chunk ^ (r&31) swizzle
  __shared__ float sl[8 * 64 * 2];    // 4 KB per-wave {absorb, atten} partials

  const int tid = threadIdx.x;
  const int lane = tid & 63;
  const int w = tid >> 6;        // wave 0..7
  const int g = lane >> 4;       // k-group 0..3 (16x16x32 frags)
  const int c = lane & 15;       // row/col within 16x16 fragment
  const int c32 = lane & 31;     // col within 32x32 fragment
  const int kg = lane >> 5;      // k-group 0..1 (32x32x16 frags)
  const int R0 = blockIdx.x * 64;
  const int bidx = R0 >> 9;      // batch index (tiles aligned within batch)

  // ---- stage Xl tile (64x64 fp32 -> bf16 LDS, swizzled; convert ONCE) ----
#pragma unroll
  for (int i = 0; i < 2; ++i) {
    int idx = i * 512 + tid;      // float4 unit 0..1023
    int r = idx >> 4;
    int c4 = idx & 15;            // 16 float4 per row
    float4 v = *reinterpret_cast<const float4*>(Xl + (size_t)(R0 + r) * FD_SZ + c4 * 4);
    bfx4 bv;
    bv[0] = f2bf(v.x); bv[1] = f2bf(v.y); bv[2] = f2bf(v.z); bv[3] = f2bf(v.w);
    int chunk = c4 >> 1;          // 8-elem (16B) chunk 0..7
    int off = r * 64 + (((chunk ^ (r & 7)) << 3) + (c4 & 1) * 4);
    *reinterpret_cast<bfx4*>(&Xs[off]) = bv;
  }
  __syncthreads();

  // ---- GEMM1 (transposed): wave computes h1 cols 16*(4w)..16*(4w+3)+15 ----
  f32x4 acc1[4][4];
#pragma unroll
  for (int mi = 0; mi < 4; ++mi)
#pragma unroll
    for (int ni = 0; ni < 4; ++ni) acc1[mi][ni] = (f32x4){0.f, 0.f, 0.f, 0.f};

#pragma unroll
  for (int ks = 0; ks < 2; ++ks) {
    bfx8 a1[4];
#pragma unroll
    for (int mi = 0; mi < 4; ++mi) {
      int mb = 4 * w + mi;
      a1[mi] = *reinterpret_cast<const bfx8*>(W1p + ((size_t)(mb * 2 + ks) * 64 + lane) * 8);
    }
    bfx8 bx[4];
#pragma unroll
    for (int ni = 0; ni < 4; ++ni) {
      int r = 16 * ni + c;
      int chunk = ks * 4 + g;
      bx[ni] = *reinterpret_cast<const bfx8*>(&Xs[r * 64 + ((chunk ^ (r & 7)) << 3)]);
    }
#pragma unroll
    for (int mi = 0; mi < 4; ++mi)
#pragma unroll
      for (int ni = 0; ni < 4; ++ni)
        acc1[mi][ni] = MFMA16(a1[mi], bx[ni], acc1[mi][ni]);
  }

  // epilogue GEMM1: bias + gelu -> bf16 -> H1s[row][k] (k = 16*mb + 4*g + reg)
#pragma unroll
  for (int mi = 0; mi < 4; ++mi) {
    int mb = 4 * w + mi;
    float4 bias4 = *reinterpret_cast<const float4*>(b1 + 16 * mb + 4 * g);
#pragma unroll
    for (int ni = 0; ni < 4; ++ni) {
      int r = 16 * ni + c;                 // x-row (0..63)
      bfx4 pv;
      pv[0] = f2bf(gelu_fast(acc1[mi][ni][0] + bias4.x));
      pv[1] = f2bf(gelu_fast(acc1[mi][ni][1] + bias4.y));
      pv[2] = f2bf(gelu_fast(acc1[mi][ni][2] + bias4.z));
      pv[3] = f2bf(gelu_fast(acc1[mi][ni][3] + bias4.w));
      int kchunk = 2 * mb + (g >> 1);      // (16*mb + 4*g)/8
      int off = r * 512 + ((kchunk ^ (r & 31)) << 3) + (g & 1) * 4;
      *reinterpret_cast<bfx4*>(&H1s[off]) = pv;
    }
  }
  __syncthreads();

  // ---- GEMM2 (32x32x16): wave w owns cols 64w..64w+63, rows 0..63 ----------
  f32x16 acc2[2][2];   // [mblk][nbk] -> 64 AGPR
#pragma unroll
  for (int m = 0; m < 2; ++m)
#pragma unroll
    for (int n = 0; n < 2; ++n)
#pragma unroll
      for (int q = 0; q < 16; ++q) acc2[m][n][q] = 0.0f;

  const __bf16* wpb = W2p + ((size_t)(2 * w) * 32 * 64 + lane) * 8;
  for (int ks = 0; ks < 32; ++ks) {
    bfx8 a2[2];
#pragma unroll
    for (int m = 0; m < 2; ++m) {
      int r = 32 * m + c32;
      int chunk = 2 * ks + kg;
      a2[m] = *reinterpret_cast<const bfx8*>(&H1s[r * 512 + ((chunk ^ (r & 31)) << 3)]);
    }
    bfx8 bw0 = *reinterpret_cast<const bfx8*>(wpb + (size_t)ks * 512);
    bfx8 bw1 = *reinterpret_cast<const bfx8*>(wpb + (size_t)16384 + ks * 512);
    __builtin_amdgcn_s_setprio(1);
    acc2[0][0] = MFMA32(a2[0], bw0, acc2[0][0]);
    acc2[0][1] = MFMA32(a2[0], bw1, acc2[0][1]);
    acc2[1][0] = MFMA32(a2[1], bw0, acc2[1][0]);
    acc2[1][1] = MFMA32(a2[1], bw1, acc2[1][1]);
    __builtin_amdgcn_s_setprio(0);
  }

  // ---- epilogue GEMM2: bias+gelu, reduce to absorb/atten/pooled ----
  // C layout (32x32): col = lane&31, row = (reg&3) + 8*(reg>>2) + 4*(lane>>5)
  float b2v[2], wav[2], wtv[2];
#pragma unroll
  for (int n = 0; n < 2; ++n) {
    int col = 32 * (2 * w + n) + c32;
    b2v[n] = b2[col];
    wav[n] = wa[col];
    wtv[n] = wt[col];
  }
  float pool0 = 0.0f, pool1 = 0.0f;
  const int rbase = 4 * kg;

#pragma unroll
  for (int m = 0; m < 2; ++m) {
#pragma unroll
    for (int reg = 0; reg < 16; ++reg) {
      float v0 = gelu_fast(acc2[m][0][reg] + b2v[0]);
      float v1 = gelu_fast(acc2[m][1][reg] + b2v[1]);
      float sa = v0 * wav[0] + v1 * wav[1];
      float st = v0 * wtv[0] + v1 * wtv[1];
      pool0 += v0;
      pool1 += v1;
      // sum over 32 cols: 16-lane DPP tree + one cross-16 shuffle
      ROR_ADD(sa, 8); ROR_ADD(sa, 4); ROR_ADD(sa, 2); ROR_ADD(sa, 1);
      ROR_ADD(st, 8); ROR_ADD(st, 4); ROR_ADD(st, 2); ROR_ADD(st, 1);
      sa += __shfl_xor(sa, 16, 64);
      st += __shfl_xor(st, 16, 64);
      if (c32 == 0) {   // lanes 0 and 32: rows rbase 0 / 4
        int row = 32 * m + (reg & 3) + 8 * (reg >> 2) + rbase;
        float2 v2 = make_float2(sa, st);
        *reinterpret_cast<float2*>(&sl[w * 128 + row * 2]) = v2;
      }
    }
  }
  // pooled: col sums need the two lane-halves (row sets) combined
  pool0 += __shfl_xor(pool0, 32, 64);
  pool1 += __shfl_xor(pool1, 32, 64);
  if (lane < 32) {
    atomicAdd(&pooled[bidx * H2_SZ + 32 * (2 * w)     + c32], pool0);
    atomicAdd(&pooled[bidx * H2_SZ + 32 * (2 * w + 1) + c32], pool1);
  }
  __syncthreads();

  if (tid < 64) {
    float sa = 0.0f, st = 0.0f;
#pragma unroll
    for (int w8 = 0; w8 < 8; ++w8) {
      float2 v2 = *reinterpret_cast<float2*>(&sl[w8 * 128 + tid * 2]);
      sa += v2.x; st += v2.y;
    }
    absorbW[R0 + tid] = softplus_f(sa + ba[0]);
    attenW[R0 + tid]  = softplus_f(st + bt[0]);
  }
}

// ---------------------------------------------------------------------------
// Finalize: per-b reversed exclusive-cumsum scan + captured, pooled head, out
// ---------------------------------------------------------------------------
__global__ __launch_bounds__(256) void finalize_kernel(
    const float* __restrict__ Xg,
    const float* __restrict__ absorbW, const float* __restrict__ attenW,
    const float* __restrict__ pooled,
    const float* __restrict__ Wd1, const float* __restrict__ bd1,
    const float* __restrict__ Wd2, const float* __restrict__ bd2,
    float* __restrict__ out) {
  __shared__ float s0[512];
  __shared__ float s1[512];
  __shared__ float sab[512];
  __shared__ float zz[544];
  __shared__ float redc[4];
  __shared__ float redd[4];

  const int b = blockIdx.x;
  const int t = threadIdx.x;
  const int i0 = t, i1 = t + 256;

  // load time-reversed absorb/atten
  float a0 = attenW[b * L_SZ + (L_SZ - 1 - i0)];
  float a1 = attenW[b * L_SZ + (L_SZ - 1 - i1)];
  sab[i0] = absorbW[b * L_SZ + (L_SZ - 1 - i0)];
  sab[i1] = absorbW[b * L_SZ + (L_SZ - 1 - i1)];
  s0[i0] = a0; s0[i1] = a1;
  __syncthreads();

  // Hillis-Steele inclusive scan (ping-pong)
  float* src = s0;
  float* dst = s1;
  for (int off = 1; off < 512; off <<= 1) {
    float v0 = src[i0] + ((i0 >= off) ? src[i0 - off] : 0.0f);
    float v1 = src[i1] + ((i1 >= off) ? src[i1 - off] : 0.0f);
    dst[i0] = v0; dst[i1] = v1;
    __syncthreads();
    float* tmp = src; src = dst; dst = tmp;
  }

  // captured partials: exp(-(incl - a)) * absorb_tb
  float p = expf(-(src[i0] - a0)) * sab[i0] + expf(-(src[i1] - a1)) * sab[i1];
#pragma unroll
  for (int off = 32; off; off >>= 1) p += __shfl_down(p, off, 64);
  if ((t & 63) == 0) redc[t >> 6] = p;

  // z = [Xg, pooled/L]
  if (t < G_SZ) zz[t] = Xg[b * G_SZ + t];
  zz[G_SZ + i0] = pooled[b * H2_SZ + i0] * (1.0f / (float)L_SZ);
  zz[G_SZ + i1] = pooled[b * H2_SZ + i1] * (1.0f / (float)L_SZ);
  __syncthreads();

  // d1[j] = gelu(z . Wd1[:,j] + bd1[j]);  v = d1[j] * Wd2[j]
  float s = bd1[t];
  for (int cc = 0; cc < G_SZ + H2_SZ; ++cc) s = fmaf(zz[cc], Wd1[cc * DH_SZ + t], s);
  float v = gelu_exact(s) * Wd2[t];
#pragma unroll
  for (int off = 32; off; off >>= 1) v += __shfl_down(v, off, 64);
  if ((t & 63) == 0) redd[t >> 6] = v;
  __syncthreads();

  if (t == 0) {
    float captured = redc[0] + redc[1] + redc[2] + redc[3];
    float d = redd[0] + redd[1] + redd[2] + redd[3] + bd2[0];
    out[b] = captured + d;
  }
}

// ---------------------------------------------------------------------------
extern "C" void kernel_launch(void* const* d_in, const int* in_sizes, int n_in,
                              void* d_out, int out_size, void* d_ws, size_t ws_size,
                              hipStream_t stream) {
  const float* Xg  = (const float*)d_in[0];
  const float* Xl  = (const float*)d_in[1];
  const float* W1  = (const float*)d_in[2];
  const float* b1  = (const float*)d_in[3];
  const float* W2  = (const float*)d_in[4];
  const float* b2  = (const float*)d_in[5];
  const float* wa  = (const float*)d_in[6];
  const float* ba  = (const float*)d_in[7];
  const float* wt  = (const float*)d_in[8];
  const float* bt  = (const float*)d_in[9];
  const float* Wd1 = (const float*)d_in[10];
  const float* bd1 = (const float*)d_in[11];
  const float* Wd2 = (const float*)d_in[12];
  const float* bd2 = (const float*)d_in[13];

  char* ws = (char*)d_ws;
  __bf16* W1p    = (__bf16*)(ws + 0);            //  65536 B
  __bf16* W2p    = (__bf16*)(ws + 65536);        // 524288 B
  float* absorbW = (float*)(ws + 589824);        // 524288 B
  float* attenW  = (float*)(ws + 1114112);       // 524288 B
  float* pooled  = (float*)(ws + 1638400);       // 524288 B  (end 2162688)

  repack_kernel<<<144, 256, 0, stream>>>(W1, W2, W1p, W2p, pooled);
  fused_kernel<<<M_SZ / 64, 512, 0, stream>>>(Xl, W1p, W2p, b1, b2, wa, ba, wt, bt,
                                              absorbW, attenW, pooled);
  finalize_kernel<<<B_SZ, 256, 0, stream>>>(Xg, absorbW, attenW, pooled,
                                            Wd1, bd1, Wd2, bd2, (float*)d_out);
}